// Round 1
// baseline (1912.789 us; speedup 1.0000x reference)
//
#include <hip/hip_runtime.h>
#include <hip/hip_bf16.h>

// Problem constants
#define B_ 16
#define C_ 512
#define K_ 64
#define N_ 4096   // H*W = 64*64
#define ALPHA0 0.5f   // sin^2(45deg)
#define BETA0  0.5f   // cos^2(45deg)

// ============================================================================
// conv 1x1 GEMM: out[b,o,n] = sum_c W[o,c] * in[b,c,n] (+ bias)
// grid (N_/128, C_/128, B_), block 256, 8x8 microtile, BK=16
// ============================================================================
template<bool BIAS>
__global__ __launch_bounds__(256)
void conv1x1_kernel(const float* __restrict__ in, const float* __restrict__ Wt,
                    const float* __restrict__ bias, float* __restrict__ out)
{
    __shared__ float As[16][128];  // As[kk][o]  (W transposed)
    __shared__ float Bs[16][128];  // Bs[kk][n]
    const int b  = blockIdx.z;
    const int n0 = blockIdx.x * 128;
    const int o0 = blockIdx.y * 128;
    const int tid = threadIdx.x;
    const int tx = tid & 15;   // n direction
    const int ty = tid >> 4;   // o direction
    const float* inB = in + (size_t)b * C_ * N_;

    float acc[8][8];
    #pragma unroll
    for (int i = 0; i < 8; ++i)
        #pragma unroll
        for (int j = 0; j < 8; ++j) acc[i][j] = 0.f;

    for (int c0 = 0; c0 < C_; c0 += 16) {
        // A tile: W[o0+row][c0..c0+16) -> transposed into As[c][o]
        #pragma unroll
        for (int l = 0; l < 2; ++l) {
            int i   = tid * 2 + l;       // 0..511
            int row = i >> 2;            // 0..127
            int c4  = (i & 3) * 4;
            float4 v = *(const float4*)(Wt + (size_t)(o0 + row) * C_ + c0 + c4);
            As[c4 + 0][row] = v.x; As[c4 + 1][row] = v.y;
            As[c4 + 2][row] = v.z; As[c4 + 3][row] = v.w;
        }
        // B tile: in[b][c0+row][n0..n0+128) -> direct copy
        #pragma unroll
        for (int l = 0; l < 2; ++l) {
            int i   = tid + l * 256;     // 0..511
            int row = i >> 5;            // 0..15
            int col = (i & 31) * 4;
            *(float4*)&Bs[row][col] =
                *(const float4*)(inB + (size_t)(c0 + row) * N_ + n0 + col);
        }
        __syncthreads();
        #pragma unroll
        for (int kk = 0; kk < 16; ++kk) {
            float a[8], bb[8];
            *(float4*)&a[0]  = *(const float4*)&As[kk][ty * 8];
            *(float4*)&a[4]  = *(const float4*)&As[kk][ty * 8 + 4];
            *(float4*)&bb[0] = *(const float4*)&Bs[kk][tx * 8];
            *(float4*)&bb[4] = *(const float4*)&Bs[kk][tx * 8 + 4];
            #pragma unroll
            for (int i = 0; i < 8; ++i)
                #pragma unroll
                for (int j = 0; j < 8; ++j)
                    acc[i][j] = fmaf(a[i], bb[j], acc[i][j]);
        }
        __syncthreads();
    }
    float* outB = out + (size_t)b * C_ * N_;
    #pragma unroll
    for (int i = 0; i < 8; ++i) {
        int o = o0 + ty * 8 + i;
        float bv = BIAS ? bias[o] : 0.f;
        #pragma unroll
        for (int j = 0; j < 8; j += 4) {
            float4 v;
            v.x = acc[i][j + 0] + bv;
            v.y = acc[i][j + 1] + bv;
            v.z = acc[i][j + 2] + bv;
            v.w = acc[i][j + 3] + bv;
            *(float4*)(outB + (size_t)o * N_ + n0 + tx * 8 + j) = v;
        }
    }
}

// ============================================================================
// init mu: mu[b,c,k] = mu0[c,k]
// ============================================================================
__global__ __launch_bounds__(256)
void initmu_kernel(const float* __restrict__ mu0, float* __restrict__ mu)
{
    int i = blockIdx.x * 256 + threadIdx.x;         // B_*C_*K_/4 float4s
    ((float4*)mu)[i] = ((const float4*)mu0)[i & (C_ * K_ / 4 - 1)];
}

// ============================================================================
// z GEMM: z[b,n,k] = sum_c xf[b,c,n] * mu[b,c,k]
// grid (N_/128, 1, B_), block 256; microtile 8(n) x 4(k), BK=16
// ============================================================================
__global__ __launch_bounds__(256)
void zgemm_kernel(const float* __restrict__ xf, const float* __restrict__ mu,
                  float* __restrict__ z)
{
    __shared__ float Xs[16][128];  // Xs[cc][n]
    __shared__ float Ms[16][64];   // Ms[cc][k]
    const int b  = blockIdx.z;
    const int n0 = blockIdx.x * 128;
    const int tid = threadIdx.x;
    const int tn = tid & 15;   // n direction (8 each)
    const int tk = tid >> 4;   // k direction (4 each)
    const float* xfB = xf + (size_t)b * C_ * N_;
    const float* muB = mu + (size_t)b * C_ * K_;

    float acc[8][4];
    #pragma unroll
    for (int i = 0; i < 8; ++i)
        #pragma unroll
        for (int j = 0; j < 4; ++j) acc[i][j] = 0.f;

    for (int c0 = 0; c0 < C_; c0 += 16) {
        #pragma unroll
        for (int l = 0; l < 2; ++l) {
            int i   = tid + l * 256;
            int row = i >> 5;
            int col = (i & 31) * 4;
            *(float4*)&Xs[row][col] =
                *(const float4*)(xfB + (size_t)(c0 + row) * N_ + n0 + col);
        }
        {
            int row = tid >> 4;          // 0..15
            int col = (tid & 15) * 4;    // 0..60
            *(float4*)&Ms[row][col] =
                *(const float4*)(muB + (size_t)(c0 + row) * K_ + col);
        }
        __syncthreads();
        #pragma unroll
        for (int kk = 0; kk < 16; ++kk) {
            float a[8], bb[4];
            *(float4*)&a[0]  = *(const float4*)&Xs[kk][tn * 8];
            *(float4*)&a[4]  = *(const float4*)&Xs[kk][tn * 8 + 4];
            *(float4*)&bb[0] = *(const float4*)&Ms[kk][tk * 4];
            #pragma unroll
            for (int i = 0; i < 8; ++i)
                #pragma unroll
                for (int j = 0; j < 4; ++j)
                    acc[i][j] = fmaf(a[i], bb[j], acc[i][j]);
        }
        __syncthreads();
    }
    float* zB = z + (size_t)b * N_ * K_;
    #pragma unroll
    for (int i = 0; i < 8; ++i) {
        int n = n0 + tn * 8 + i;
        float4 v; v.x = acc[i][0]; v.y = acc[i][1]; v.z = acc[i][2]; v.w = acc[i][3];
        *(float4*)(zB + (size_t)n * K_ + tk * 4) = v;
    }
}

// ============================================================================
// softmax/blend per (b,n) row over k: z = 0.5*softmax(z) + 0.5*64/(63+2*||z||)
// one wave per row
// ============================================================================
__global__ __launch_bounds__(256)
void softmax_blend_kernel(float* __restrict__ z)
{
    int row  = (blockIdx.x * 256 + threadIdx.x) >> 6;  // b*N_+n
    int lane = threadIdx.x & 63;
    float* p = z + (size_t)row * K_;
    float v = p[lane];
    float m = v;
    #pragma unroll
    for (int off = 32; off > 0; off >>= 1) m = fmaxf(m, __shfl_xor(m, off));
    float e = expf(v - m);
    float se = e, sq = v * v;
    #pragma unroll
    for (int off = 32; off > 0; off >>= 1) {
        se += __shfl_xor(se, off);
        sq += __shfl_xor(sq, off);
    }
    float nrm = sqrtf(sq);
    p[lane] = ALPHA0 * e / se + BETA0 * (float)K_ / ((float)(K_ - 1) + 2.f * nrm);
}

// ============================================================================
// column sums over n: invcs[b,k] = 1/(1e-6 + sum_n z[b,n,k])
// one block per b
// ============================================================================
__global__ __launch_bounds__(256)
void colsum_kernel(const float* __restrict__ z, float* __restrict__ invcs)
{
    int b = blockIdx.x;
    int tid = threadIdx.x;
    int k = tid & 63, part = tid >> 6;   // 4 partitions over n
    const float* zB = z + (size_t)b * N_ * K_;
    float s = 0.f;
    for (int n = part; n < N_; n += 4) s += zB[(size_t)n * K_ + k];
    __shared__ float red[4][64];
    red[part][k] = s;
    __syncthreads();
    if (part == 0) {
        float t = red[0][k] + red[1][k] + red[2][k] + red[3][k];
        invcs[b * K_ + k] = 1.f / (1e-6f + t);
    }
}

// ============================================================================
// mu GEMM (split-K over n): macc[b,c,k] += invcs[k]*sum_{n chunk} xf[b,c,n]*z[b,n,k]
// grid (8 nchunks, C_/128, B_), block 256; microtile 8(c) x 4(k)
// ============================================================================
__global__ __launch_bounds__(256)
void mugemm_kernel(const float* __restrict__ xf, const float* __restrict__ z,
                   const float* __restrict__ invcs, float* __restrict__ macc)
{
    __shared__ float As[16][128];  // As[nn][c]
    __shared__ float Bs[16][64];   // Bs[nn][k]
    const int b  = blockIdx.z;
    const int c0 = blockIdx.y * 128;
    const int nb = blockIdx.x * 512;
    const int tid = threadIdx.x;
    const int tk = tid & 15;   // k direction (4 each)
    const int tc = tid >> 4;   // c direction (8 each)
    const float* xfB = xf + (size_t)b * C_ * N_;
    const float* zB  = z  + (size_t)b * N_ * K_;

    float acc[8][4];
    #pragma unroll
    for (int i = 0; i < 8; ++i)
        #pragma unroll
        for (int j = 0; j < 4; ++j) acc[i][j] = 0.f;

    for (int nn0 = 0; nn0 < 512; nn0 += 16) {
        // A tile: xf[b][c0+row][nb+nn0 .. +16) -> transposed As[nn][c]
        #pragma unroll
        for (int l = 0; l < 2; ++l) {
            int i   = tid * 2 + l;
            int row = i >> 2;            // 0..127 (c)
            int n4  = (i & 3) * 4;
            float4 v = *(const float4*)(xfB + (size_t)(c0 + row) * N_ + nb + nn0 + n4);
            As[n4 + 0][row] = v.x; As[n4 + 1][row] = v.y;
            As[n4 + 2][row] = v.z; As[n4 + 3][row] = v.w;
        }
        // B tile: z[b][nb+nn0+row][0..64) -> direct
        {
            int row = tid >> 4;
            int col = (tid & 15) * 4;
            *(float4*)&Bs[row][col] =
                *(const float4*)(zB + (size_t)(nb + nn0 + row) * K_ + col);
        }
        __syncthreads();
        #pragma unroll
        for (int nn = 0; nn < 16; ++nn) {
            float a[8], bb[4];
            *(float4*)&a[0]  = *(const float4*)&As[nn][tc * 8];
            *(float4*)&a[4]  = *(const float4*)&As[nn][tc * 8 + 4];
            *(float4*)&bb[0] = *(const float4*)&Bs[nn][tk * 4];
            #pragma unroll
            for (int i = 0; i < 8; ++i)
                #pragma unroll
                for (int j = 0; j < 4; ++j)
                    acc[i][j] = fmaf(a[i], bb[j], acc[i][j]);
        }
        __syncthreads();
    }
    #pragma unroll
    for (int j = 0; j < 4; ++j) {
        int k = tk * 4 + j;
        float ic = invcs[b * K_ + k];
        #pragma unroll
        for (int i = 0; i < 8; ++i) {
            int c = c0 + tc * 8 + i;
            atomicAdd(&macc[(size_t)b * C_ * K_ + (size_t)c * K_ + k], acc[i][j] * ic);
        }
    }
}

// ============================================================================
// l2 normalize mu columns over c: mu[b,:,k] = macc[b,:,k]/(1e-6+||macc[b,:,k]||)
// one wave per (b,k)
// ============================================================================
__global__ __launch_bounds__(256)
void l2norm_kernel(const float* __restrict__ macc, float* __restrict__ mu)
{
    int wid  = blockIdx.x * 4 + (threadIdx.x >> 6);   // 0..B_*K_-1
    int lane = threadIdx.x & 63;
    int b = wid >> 6;          // / K_
    int k = wid & (K_ - 1);
    const float* src = macc + (size_t)b * C_ * K_ + k;
    float*       dst = mu   + (size_t)b * C_ * K_ + k;
    float v[8];
    float s = 0.f;
    #pragma unroll
    for (int i = 0; i < 8; ++i) {
        v[i] = src[(size_t)(lane + i * 64) * K_];
        s += v[i] * v[i];
    }
    #pragma unroll
    for (int off = 32; off > 0; off >>= 1) s += __shfl_xor(s, off);
    float inv = 1.f / (1e-6f + sqrtf(s));
    #pragma unroll
    for (int i = 0; i < 8; ++i) dst[(size_t)(lane + i * 64) * K_] = v[i] * inv;
}

// ============================================================================
// reconstruction: xr[b,c,n] = relu(sum_k mu[b,c,k] * z[b,n,k])
// grid (N_/128, C_/128, B_), block 256, 8x8 microtile, BK=16 (4 iters over K=64)
// ============================================================================
__global__ __launch_bounds__(256)
void recon_kernel(const float* __restrict__ mu, const float* __restrict__ z,
                  float* __restrict__ xr)
{
    __shared__ float As[16][128];  // As[kk][c]
    __shared__ float Bs[16][128];  // Bs[kk][n]
    const int b  = blockIdx.z;
    const int n0 = blockIdx.x * 128;
    const int c0 = blockIdx.y * 128;
    const int tid = threadIdx.x;
    const int tx = tid & 15;   // n
    const int ty = tid >> 4;   // c
    const float* muB = mu + (size_t)b * C_ * K_;
    const float* zB  = z  + (size_t)b * N_ * K_;

    float acc[8][8];
    #pragma unroll
    for (int i = 0; i < 8; ++i)
        #pragma unroll
        for (int j = 0; j < 8; ++j) acc[i][j] = 0.f;

    for (int k0 = 0; k0 < K_; k0 += 16) {
        #pragma unroll
        for (int l = 0; l < 2; ++l) {
            int i   = tid * 2 + l;
            int row = i >> 2;            // 0..127
            int k4  = (i & 3) * 4;
            float4 v = *(const float4*)(muB + (size_t)(c0 + row) * K_ + k0 + k4);
            As[k4 + 0][row] = v.x; As[k4 + 1][row] = v.y;
            As[k4 + 2][row] = v.z; As[k4 + 3][row] = v.w;
        }
        #pragma unroll
        for (int l = 0; l < 2; ++l) {
            int i   = tid * 2 + l;
            int row = i >> 2;
            int k4  = (i & 3) * 4;
            float4 v = *(const float4*)(zB + (size_t)(n0 + row) * K_ + k0 + k4);
            Bs[k4 + 0][row] = v.x; Bs[k4 + 1][row] = v.y;
            Bs[k4 + 2][row] = v.z; Bs[k4 + 3][row] = v.w;
        }
        __syncthreads();
        #pragma unroll
        for (int kk = 0; kk < 16; ++kk) {
            float a[8], bb[8];
            *(float4*)&a[0]  = *(const float4*)&As[kk][ty * 8];
            *(float4*)&a[4]  = *(const float4*)&As[kk][ty * 8 + 4];
            *(float4*)&bb[0] = *(const float4*)&Bs[kk][tx * 8];
            *(float4*)&bb[4] = *(const float4*)&Bs[kk][tx * 8 + 4];
            #pragma unroll
            for (int i = 0; i < 8; ++i)
                #pragma unroll
                for (int j = 0; j < 8; ++j)
                    acc[i][j] = fmaf(a[i], bb[j], acc[i][j]);
        }
        __syncthreads();
    }
    float* xrB = xr + (size_t)b * C_ * N_;
    #pragma unroll
    for (int i = 0; i < 8; ++i) {
        int c = c0 + ty * 8 + i;
        #pragma unroll
        for (int j = 0; j < 8; j += 4) {
            float4 v;
            v.x = fmaxf(acc[i][j + 0], 0.f);
            v.y = fmaxf(acc[i][j + 1], 0.f);
            v.z = fmaxf(acc[i][j + 2], 0.f);
            v.w = fmaxf(acc[i][j + 3], 0.f);
            *(float4*)(xrB + (size_t)c * N_ + n0 + tx * 8 + j) = v;
        }
    }
}

// ============================================================================
// BN stats: per-channel mean/var over (b,n) -> scale/shift. One block per o.
// ============================================================================
__global__ __launch_bounds__(256)
void bnstats_kernel(const float* __restrict__ y, const float* __restrict__ gamma,
                    const float* __restrict__ beta, float* __restrict__ bnscale,
                    float* __restrict__ bnshift)
{
    int o = blockIdx.x;
    int tid = threadIdx.x;
    float s = 0.f, sq = 0.f;
    for (int b = 0; b < B_; ++b) {
        const float4* p = (const float4*)(y + ((size_t)b * C_ + o) * N_);
        for (int i = tid; i < N_ / 4; i += 256) {
            float4 v = p[i];
            s  += v.x + v.y + v.z + v.w;
            sq += v.x * v.x + v.y * v.y + v.z * v.z + v.w * v.w;
        }
    }
    #pragma unroll
    for (int off = 32; off > 0; off >>= 1) {
        s  += __shfl_xor(s, off);
        sq += __shfl_xor(sq, off);
    }
    __shared__ float rs[4], rq[4];
    int wid = tid >> 6, lane = tid & 63;
    if (lane == 0) { rs[wid] = s; rq[wid] = sq; }
    __syncthreads();
    if (tid == 0) {
        float ts = rs[0] + rs[1] + rs[2] + rs[3];
        float tq = rq[0] + rq[1] + rq[2] + rq[3];
        const float inv_n = 1.f / (float)(B_ * N_);
        float mean = ts * inv_n;
        float var  = tq * inv_n - mean * mean;
        float istd = rsqrtf(var + 1e-5f);
        bnscale[o] = gamma[o] * istd;
        bnshift[o] = beta[o] - gamma[o] * istd * mean;
    }
}

// ============================================================================
// final: out = relu(y*scale + shift + x), in place over y (= d_out)
// ============================================================================
__global__ __launch_bounds__(256)
void bnout_kernel(float* __restrict__ y, const float* __restrict__ x,
                  const float* __restrict__ bnscale, const float* __restrict__ bnshift)
{
    size_t i = (size_t)blockIdx.x * 256 + threadIdx.x;   // float4 index
    float4 vy = ((float4*)y)[i];
    float4 vx = ((const float4*)x)[i];
    int o = (int)((i >> 10) & (C_ - 1));                 // (i*4 / N_) % C_
    float sc = bnscale[o], sh = bnshift[o];
    float4 r;
    r.x = fmaxf(fmaf(vy.x, sc, sh) + vx.x, 0.f);
    r.y = fmaxf(fmaf(vy.y, sc, sh) + vx.y, 0.f);
    r.z = fmaxf(fmaf(vy.z, sc, sh) + vx.z, 0.f);
    r.w = fmaxf(fmaf(vy.w, sc, sh) + vx.w, 0.f);
    ((float4*)y)[i] = r;
}

// ============================================================================
// copy mu into output region + write theta
// ============================================================================
__global__ __launch_bounds__(256)
void copymu_kernel(const float* __restrict__ mu, float* __restrict__ dst,
                   float* __restrict__ theta_dst)
{
    int i = blockIdx.x * 256 + threadIdx.x;   // B_*C_*K_/4 float4s
    ((float4*)dst)[i] = ((const float4*)mu)[i];
    if (i == 0) *theta_dst = 45.0f;
}

// ============================================================================
extern "C" void kernel_launch(void* const* d_in, const int* in_sizes, int n_in,
                              void* d_out, int out_size, void* d_ws, size_t ws_size,
                              hipStream_t stream)
{
    const float* x     = (const float*)d_in[0];
    const float* W1    = (const float*)d_in[1];
    const float* b1    = (const float*)d_in[2];
    const float* W2    = (const float*)d_in[3];
    const float* gamma = (const float*)d_in[4];
    const float* beta  = (const float*)d_in[5];
    const float* mu0   = (const float*)d_in[6];

    // workspace layout (floats): ~155 MB total
    float* ws     = (float*)d_ws;
    float* xf     = ws;                                   // B*C*N (reused as xr)
    float* z      = xf   + (size_t)B_ * C_ * N_;          // B*N*K
    float* macc   = z    + (size_t)B_ * N_ * K_;          // B*C*K (unnormalized mu)
    float* mu     = macc + (size_t)B_ * C_ * K_;          // B*C*K
    float* invcs  = mu   + (size_t)B_ * C_ * K_;          // B*K
    float* bnscale = invcs + B_ * K_;                     // C
    float* bnshift = bnscale + C_;                        // C

    // y (conv2 out) lives in the d_out "out" region; BN applied in place.
    float* y         = (float*)d_out;
    float* mu_out    = (float*)d_out + (size_t)B_ * C_ * N_;
    float* theta_out = mu_out + (size_t)B_ * C_ * K_;

    dim3 blk(256);

    // mu[b] = mu0
    initmu_kernel<<<dim3(B_ * C_ * K_ / 4 / 256), blk, 0, stream>>>(mu0, mu);
    // conv1: xf = W1 @ x + b1
    conv1x1_kernel<true><<<dim3(N_ / 128, C_ / 128, B_), blk, 0, stream>>>(x, W1, b1, xf);

    for (int s = 0; s < 2; ++s) {
        // z = xf^T @ mu
        zgemm_kernel<<<dim3(N_ / 128, 1, B_), blk, 0, stream>>>(xf, mu, z);
        // blend softmax + power-law term
        softmax_blend_kernel<<<dim3(B_ * N_ / 4), blk, 0, stream>>>(z);
        // column sums over n
        colsum_kernel<<<dim3(B_), blk, 0, stream>>>(z, invcs);
        // mu' = xf @ (z * invcs) via split-K atomics
        hipMemsetAsync(macc, 0, (size_t)B_ * C_ * K_ * sizeof(float), stream);
        mugemm_kernel<<<dim3(8, C_ / 128, B_), blk, 0, stream>>>(xf, z, invcs, macc);
        // l2 normalize columns
        l2norm_kernel<<<dim3(B_ * K_ / 4), blk, 0, stream>>>(macc, mu);
    }

    // xr = relu(mu @ z^T), overwrites xf
    recon_kernel<<<dim3(N_ / 128, C_ / 128, B_), blk, 0, stream>>>(mu, z, xf);
    // y = W2 @ xr   (into d_out region)
    conv1x1_kernel<false><<<dim3(N_ / 128, C_ / 128, B_), blk, 0, stream>>>(xf, W2, nullptr, y);
    // BN stats -> scale/shift
    bnstats_kernel<<<dim3(C_), blk, 0, stream>>>(y, gamma, beta, bnscale, bnshift);
    // out = relu(y*scale + shift + x), in place
    bnout_kernel<<<dim3(B_ * C_ * N_ / 4 / 256), blk, 0, stream>>>(y, x, bnscale, bnshift);
    // mu + theta outputs
    copymu_kernel<<<dim3(B_ * C_ * K_ / 4 / 256), blk, 0, stream>>>(mu, mu_out, theta_out);
}

// Round 3
// 611.924 us; speedup vs baseline: 3.1259x; 3.1259x over previous
//
#include <hip/hip_runtime.h>
#include <hip/hip_bf16.h>

#define B_ 16
#define C_ 512
#define K_ 64
#define N_ 4096   // H*W
#define LDA 40    // 32 shorts + 8 pad: row stride 80B -> <=2-way bank aliasing (free)

typedef unsigned short ushort_t;
typedef __attribute__((ext_vector_type(8))) short s16x8;
typedef __attribute__((ext_vector_type(4))) short s16x4;
typedef __attribute__((ext_vector_type(4))) float f32x4;

__device__ inline ushort_t f2bf(float f) {            // RNE
    unsigned int u = __builtin_bit_cast(unsigned int, f);
    u = (u + 0x7FFFu + ((u >> 16) & 1u)) >> 16;
    return (ushort_t)u;
}
__device__ inline ushort_t f2bf_fast(float f) {       // round-half-up (bulk staging)
    unsigned int u = __builtin_bit_cast(unsigned int, f);
    return (ushort_t)((u + 0x8000u) >> 16);
}
__device__ inline float bf2f(ushort_t h) {
    unsigned int u = ((unsigned int)h) << 16;
    return __builtin_bit_cast(float, u);
}

// Stage R x 32 bf16 tile (row-major, contraction contiguous) into padded LDS.
template<int R>
__device__ inline void stage_tile(ushort_t* lds, const ushort_t* g, int gstride) {
    const int t = threadIdx.x;
    #pragma unroll
    for (int l = 0; l < R / 64; ++l) {
        int ch = t + l * 256;
        int row = ch >> 2, seg = ch & 3;
        s16x8 v = *(const s16x8*)(g + (size_t)row * gstride + seg * 8);
        *(s16x8*)(lds + row * LDA + seg * 8) = v;
    }
}

// Stage 64 x 32 fp32 tile -> bf16 LDS (RNE; used for post-softmax z)
__device__ inline void stage_zf(ushort_t* lds, const float* g, int gstride) {
    const int t = threadIdx.x;
    #pragma unroll
    for (int l = 0; l < 2; ++l) {
        int ch = t + l * 256;            // 512 chunks
        int row = ch >> 3, seg = ch & 7; // 64 rows, 8 segs of 4 floats
        float4 f = *(const float4*)(g + (size_t)row * gstride + seg * 4);
        s16x4 v;
        v[0] = (short)f2bf(f.x); v[1] = (short)f2bf(f.y);
        v[2] = (short)f2bf(f.z); v[3] = (short)f2bf(f.w);
        *(s16x4*)(lds + row * LDA + seg * 4) = v;
    }
}

// ============================================================================
// cvt W1,W2 -> bf16
// ============================================================================
__global__ __launch_bounds__(256)
void cvtW_kernel(const float* __restrict__ W1, const float* __restrict__ W2,
                 ushort_t* __restrict__ W1b, ushort_t* __restrict__ W2b)
{
    int idx = blockIdx.x * 256 + threadIdx.x;   // 0..65535, 8 floats each
    const float* s; ushort_t* d; int off;
    if (idx < 32768) { s = W1; d = W1b; off = idx * 8; }
    else             { s = W2; d = W2b; off = (idx - 32768) * 8; }
    float4 a = *(const float4*)(s + off);
    float4 b = *(const float4*)(s + off + 4);
    s16x8 v;
    v[0] = (short)f2bf(a.x); v[1] = (short)f2bf(a.y);
    v[2] = (short)f2bf(a.z); v[3] = (short)f2bf(a.w);
    v[4] = (short)f2bf(b.x); v[5] = (short)f2bf(b.y);
    v[6] = (short)f2bf(b.z); v[7] = (short)f2bf(b.w);
    *(s16x8*)(d + off) = v;
}

// ============================================================================
// initmu: mu0 fp32 [c][k] -> mu_t bf16 [k][c]
// ============================================================================
__global__ __launch_bounds__(256)
void initmu_kernel(const float* __restrict__ mu0, ushort_t* __restrict__ mu_t)
{
    int idx = blockIdx.x * 256 + threadIdx.x;   // c = idx>>6, k = idx&63
    float v = mu0[idx];
    mu_t[(idx & 63) * C_ + (idx >> 6)] = f2bf(v);
}

// ============================================================================
// conv1: xf[b][o][n] bf16 = sum_c W1[o,c]*x[b,c,n] + b1[o]; also xft [n][o].
// A = W1b[o][c] bf16; B staged by in-kernel transpose of fp32 x (4x4 reg blocks)
// grid (32, 4, 16), 256 thr, 4 waves (2x2), wave 64x64
// ============================================================================
__global__ __launch_bounds__(256)
void conv1_mfma(const ushort_t* __restrict__ W1b, const float* __restrict__ x,
                const float* __restrict__ b1, ushort_t* __restrict__ xf,
                ushort_t* __restrict__ xft)
{
    __shared__ ushort_t As[128 * LDA];
    __shared__ ushort_t Bs[128 * LDA];
    const int n0 = blockIdx.x * 128;
    const int o0 = blockIdx.y * 128;
    const int b  = blockIdx.z;
    const int t  = threadIdx.x;
    const int wid = t >> 6, lane = t & 63;
    const int wm = wid >> 1, wn = wid & 1;
    const int l15 = lane & 15, q = lane >> 4;

    const ushort_t* gA = W1b + (size_t)o0 * C_;
    const float*    xB = x + (size_t)b * C_ * N_ + n0;
    const int cg = t >> 5, ng = t & 31;   // transpose-stage coords

    f32x4 acc[4][4] = {};

    for (int c0 = 0; c0 < C_; c0 += 32) {
        __syncthreads();
        stage_tile<128>(As, gA + c0, C_);
        {   // B: transpose-stage x[c0+cg*4 .. +4)[n0+ng*4 .. +4) -> Bs[n][c]
            const float* src = xB + (size_t)(c0 + cg * 4) * N_ + ng * 4;
            float4 f0 = *(const float4*)(src);
            float4 f1 = *(const float4*)(src + N_);
            float4 f2 = *(const float4*)(src + 2 * N_);
            float4 f3 = *(const float4*)(src + 3 * N_);
            ushort_t* dst = Bs + (ng * 4) * LDA + cg * 4;
            s16x4 v;
            v[0] = (short)f2bf_fast(f0.x); v[1] = (short)f2bf_fast(f1.x);
            v[2] = (short)f2bf_fast(f2.x); v[3] = (short)f2bf_fast(f3.x);
            *(s16x4*)(dst) = v;
            v[0] = (short)f2bf_fast(f0.y); v[1] = (short)f2bf_fast(f1.y);
            v[2] = (short)f2bf_fast(f2.y); v[3] = (short)f2bf_fast(f3.y);
            *(s16x4*)(dst + LDA) = v;
            v[0] = (short)f2bf_fast(f0.z); v[1] = (short)f2bf_fast(f1.z);
            v[2] = (short)f2bf_fast(f2.z); v[3] = (short)f2bf_fast(f3.z);
            *(s16x4*)(dst + 2 * LDA) = v;
            v[0] = (short)f2bf_fast(f0.w); v[1] = (short)f2bf_fast(f1.w);
            v[2] = (short)f2bf_fast(f2.w); v[3] = (short)f2bf_fast(f3.w);
            *(s16x4*)(dst + 3 * LDA) = v;
        }
        __syncthreads();
        s16x8 af[4], bf[4];
        #pragma unroll
        for (int m = 0; m < 4; ++m)
            af[m] = *(const s16x8*)&As[(wm * 64 + m * 16 + l15) * LDA + q * 8];
        #pragma unroll
        for (int n = 0; n < 4; ++n)
            bf[n] = *(const s16x8*)&Bs[(wn * 64 + n * 16 + l15) * LDA + q * 8];
        #pragma unroll
        for (int m = 0; m < 4; ++m)
            #pragma unroll
            for (int n = 0; n < 4; ++n)
                acc[m][n] = __builtin_amdgcn_mfma_f32_16x16x32_bf16(af[m], bf[n], acc[m][n], 0, 0, 0);
    }

    ushort_t* xfB  = xf  + (size_t)b * C_ * N_;
    ushort_t* xftB = xft + (size_t)b * N_ * C_;
    #pragma unroll
    for (int m = 0; m < 4; ++m) {
        int obase = o0 + wm * 64 + m * 16 + 4 * q;
        float bv[4];
        #pragma unroll
        for (int r = 0; r < 4; ++r) bv[r] = b1[obase + r];
        #pragma unroll
        for (int n = 0; n < 4; ++n) {
            int nn = n0 + wn * 64 + n * 16 + l15;
            s16x4 pk;
            #pragma unroll
            for (int r = 0; r < 4; ++r) {
                ushort_t h = f2bf(acc[m][n][r] + bv[r]);
                pk[r] = (short)h;
                xfB[(size_t)(obase + r) * N_ + nn] = h;
            }
            *(s16x4*)&xftB[(size_t)nn * C_ + obase] = pk;
        }
    }
}

// ============================================================================
// zgemm: zst[b][k][n] fp32 = sum_c mu[c,k]*xf[c,n]
// A = mu_t[k][c] bf16 (batch stride param), Bt = xft[n][c] bf16
// grid (32, 1, 16); wave tile 32(k) x 64(n)
// ============================================================================
__global__ __launch_bounds__(256)
void zgemm_mfma(const ushort_t* __restrict__ mu_t, const ushort_t* __restrict__ xft,
                float* __restrict__ zst, int mustride)
{
    __shared__ ushort_t As[64 * LDA];
    __shared__ ushort_t Bs[128 * LDA];
    const int n0 = blockIdx.x * 128;
    const int b  = blockIdx.z;
    const int t  = threadIdx.x;
    const int wid = t >> 6, lane = t & 63;
    const int wm = wid >> 1, wn = wid & 1;
    const int l15 = lane & 15, q = lane >> 4;

    const ushort_t* gA = mu_t + (size_t)b * mustride;
    const ushort_t* gB = xft + (size_t)b * N_ * C_ + (size_t)n0 * C_;

    f32x4 acc[2][4] = {};

    for (int c0 = 0; c0 < C_; c0 += 32) {
        __syncthreads();
        stage_tile<64>(As, gA + c0, C_);
        stage_tile<128>(Bs, gB + c0, C_);
        __syncthreads();
        s16x8 af[2], bf[4];
        #pragma unroll
        for (int m = 0; m < 2; ++m)
            af[m] = *(const s16x8*)&As[(wm * 32 + m * 16 + l15) * LDA + q * 8];
        #pragma unroll
        for (int n = 0; n < 4; ++n)
            bf[n] = *(const s16x8*)&Bs[(wn * 64 + n * 16 + l15) * LDA + q * 8];
        #pragma unroll
        for (int m = 0; m < 2; ++m)
            #pragma unroll
            for (int n = 0; n < 4; ++n)
                acc[m][n] = __builtin_amdgcn_mfma_f32_16x16x32_bf16(af[m], bf[n], acc[m][n], 0, 0, 0);
    }

    float* zB = zst + (size_t)b * K_ * N_;
    #pragma unroll
    for (int m = 0; m < 2; ++m) {
        int kbase = wm * 32 + m * 16 + 4 * q;
        #pragma unroll
        for (int n = 0; n < 4; ++n) {
            int nn = n0 + wn * 64 + n * 16 + l15;
            #pragma unroll
            for (int r = 0; r < 4; ++r)
                zB[(size_t)(kbase + r) * N_ + nn] = acc[m][n][r];
        }
    }
}

// ============================================================================
// softmax/blend per column n over k (fp32, in place): thread-per-column
// z = 0.5*softmax(z) + 0.5*64/(63+2*||z||)
// ============================================================================
__global__ __launch_bounds__(256)
void softmax_col(float* __restrict__ zst)
{
    const int b = blockIdx.y;
    const int n = blockIdx.x * 256 + threadIdx.x;
    float* p = zst + (size_t)b * K_ * N_ + n;
    float v[K_];
    float m = -1e30f, sq = 0.f;
    #pragma unroll
    for (int k = 0; k < K_; ++k) {
        v[k] = p[(size_t)k * N_];
        m = fmaxf(m, v[k]);
        sq += v[k] * v[k];
    }
    float se = 0.f;
    #pragma unroll
    for (int k = 0; k < K_; ++k) { v[k] = expf(v[k] - m); se += v[k]; }
    float inv_se = 0.5f / se;
    float bl = 0.5f * (float)K_ / ((float)(K_ - 1) + 2.f * sqrtf(sq));
    #pragma unroll
    for (int k = 0; k < K_; ++k)
        p[(size_t)k * N_] = v[k] * inv_se + bl;
}

// ============================================================================
// colsum over n: invcs[b,k] = 1/(1e-6 + sum_n zst[k][n]); wave per (b,k)
// ============================================================================
__global__ __launch_bounds__(256)
void colsum_t(const float* __restrict__ zst, float* __restrict__ invcs)
{
    int wid  = blockIdx.x * 4 + (threadIdx.x >> 6);   // 0..B*K-1
    int lane = threadIdx.x & 63;
    int b = wid >> 6, k = wid & 63;
    const float* p = zst + (size_t)b * K_ * N_ + (size_t)k * N_;
    float s = 0.f;
    #pragma unroll 8
    for (int i = 0; i < 64; ++i) s += p[lane + i * 64];
    #pragma unroll
    for (int off = 32; off > 0; off >>= 1) s += __shfl_xor(s, off);
    if (lane == 0) invcs[b * K_ + k] = 1.f / (1e-6f + s);
}

// ============================================================================
// mugemm: macc[b][k][c] fp32 (atomic) += invcs[k]*sum_n z[k,n]*xf[c,n]
// A = zst fp32->bf16 staged, Bt = xf[c][n] bf16; split over n: grid (8, 4, 16)
// ============================================================================
__global__ __launch_bounds__(256)
void mugemm_mfma(const float* __restrict__ zst, const ushort_t* __restrict__ xf,
                 const float* __restrict__ invcs, float* __restrict__ macc)
{
    __shared__ ushort_t As[64 * LDA];
    __shared__ ushort_t Bs[128 * LDA];
    const int ns = blockIdx.x * 512;
    const int c0 = blockIdx.y * 128;
    const int b  = blockIdx.z;
    const int t  = threadIdx.x;
    const int wid = t >> 6, lane = t & 63;
    const int wm = wid >> 1, wn = wid & 1;
    const int l15 = lane & 15, q = lane >> 4;

    const float*    gA = zst + (size_t)b * K_ * N_ + ns;
    const ushort_t* gB = xf + (size_t)b * C_ * N_ + (size_t)c0 * N_ + ns;

    f32x4 acc[2][4] = {};

    for (int nn0 = 0; nn0 < 512; nn0 += 32) {
        __syncthreads();
        stage_zf(As, gA + nn0, N_);
        stage_tile<128>(Bs, gB + nn0, N_);
        __syncthreads();
        s16x8 af[2], bf[4];
        #pragma unroll
        for (int m = 0; m < 2; ++m)
            af[m] = *(const s16x8*)&As[(wm * 32 + m * 16 + l15) * LDA + q * 8];
        #pragma unroll
        for (int n = 0; n < 4; ++n)
            bf[n] = *(const s16x8*)&Bs[(wn * 64 + n * 16 + l15) * LDA + q * 8];
        #pragma unroll
        for (int m = 0; m < 2; ++m)
            #pragma unroll
            for (int n = 0; n < 4; ++n)
                acc[m][n] = __builtin_amdgcn_mfma_f32_16x16x32_bf16(af[m], bf[n], acc[m][n], 0, 0, 0);
    }

    float* mB = macc + (size_t)b * K_ * C_;
    #pragma unroll
    for (int m = 0; m < 2; ++m) {
        int kbase = wm * 32 + m * 16 + 4 * q;
        float ic[4];
        #pragma unroll
        for (int r = 0; r < 4; ++r) ic[r] = invcs[b * K_ + kbase + r];
        #pragma unroll
        for (int n = 0; n < 4; ++n) {
            int cc = c0 + wn * 64 + n * 16 + l15;
            #pragma unroll
            for (int r = 0; r < 4; ++r)
                atomicAdd(&mB[(size_t)(kbase + r) * C_ + cc], acc[m][n][r] * ic[r]);
        }
    }
}

// ============================================================================
// l2norm over c: mu_t bf16 [k][c], mu_b bf16 [c][k], mu_out fp32 [c][k], theta
// wave per (b,k)
// ============================================================================
__global__ __launch_bounds__(256)
void l2norm_t(const float* __restrict__ macc, ushort_t* __restrict__ mu_t,
              ushort_t* __restrict__ mu_b, float* __restrict__ mu_out,
              float* __restrict__ theta_out)
{
    int wid  = blockIdx.x * 4 + (threadIdx.x >> 6);
    int lane = threadIdx.x & 63;
    int b = wid >> 6, k = wid & 63;
    const float* src = macc + (size_t)b * K_ * C_ + (size_t)k * C_;
    float v[8], s = 0.f;
    #pragma unroll
    for (int i = 0; i < 8; ++i) { v[i] = src[lane + i * 64]; s += v[i] * v[i]; }
    #pragma unroll
    for (int off = 32; off > 0; off >>= 1) s += __shfl_xor(s, off);
    float inv = 1.f / (1e-6f + sqrtf(s));
    ushort_t* mt = mu_t + (size_t)b * K_ * C_ + (size_t)k * C_;
    ushort_t* mb = mu_b + (size_t)b * C_ * K_ + k;
    float*    mo = mu_out + (size_t)b * C_ * K_ + k;
    #pragma unroll
    for (int i = 0; i < 8; ++i) {
        int c = lane + i * 64;
        float val = v[i] * inv;
        mt[c] = f2bf(val);
        mb[(size_t)c * K_] = f2bf(val);
        mo[(size_t)c * K_] = val;
    }
    if (wid == 0 && lane == 0) *theta_out = 45.0f;
}

// ============================================================================
// ztr: zst fp32 [k][n] -> zs bf16 [n][k], 64x64 LDS tiles
// ============================================================================
__global__ __launch_bounds__(256)
void ztr_kernel(const float* __restrict__ zst, ushort_t* __restrict__ zs)
{
    __shared__ ushort_t lds[64 * 72];
    const int n0 = blockIdx.x * 64;
    const int b  = blockIdx.y;
    const int t  = threadIdx.x;
    const float* src = zst + (size_t)b * K_ * N_;
    #pragma unroll
    for (int i = 0; i < 4; ++i) {
        int ch = t + 256 * i;              // 1024 chunks
        int krow = ch >> 4, seg = ch & 15; // 64 k-rows, 16 segs of 4 n
        float4 f = *(const float4*)(src + (size_t)krow * N_ + n0 + seg * 4);
        lds[(seg * 4 + 0) * 72 + krow] = f2bf(f.x);
        lds[(seg * 4 + 1) * 72 + krow] = f2bf(f.y);
        lds[(seg * 4 + 2) * 72 + krow] = f2bf(f.z);
        lds[(seg * 4 + 3) * 72 + krow] = f2bf(f.w);
    }
    __syncthreads();
    ushort_t* dst = zs + (size_t)b * N_ * K_;
    #pragma unroll
    for (int i = 0; i < 2; ++i) {
        int ch = t + 256 * i;
        int row = ch >> 3, seg = ch & 7;
        s16x8 v = *(const s16x8*)&lds[row * 72 + seg * 8];
        *(s16x8*)(dst + (size_t)(n0 + row) * K_ + seg * 8) = v;
    }
}

// ============================================================================
// recon: xrt[n][c] bf16 = relu(sum_k mu[c,k]*z[n,k])
// A = mu_b[c][k], Bt = zs[n][k]; grid (32, 4, 16)
// ============================================================================
__global__ __launch_bounds__(256)
void recon_mfma(const ushort_t* __restrict__ mu_b, const ushort_t* __restrict__ zs,
                ushort_t* __restrict__ xrt)
{
    __shared__ ushort_t As[128 * LDA];
    __shared__ ushort_t Bs[128 * LDA];
    const int n0 = blockIdx.x * 128;
    const int c0 = blockIdx.y * 128;
    const int b  = blockIdx.z;
    const int t  = threadIdx.x;
    const int wid = t >> 6, lane = t & 63;
    const int wm = wid >> 1, wn = wid & 1;
    const int l15 = lane & 15, q = lane >> 4;

    const ushort_t* gA = mu_b + (size_t)b * C_ * K_ + (size_t)c0 * K_;
    const ushort_t* gB = zs + (size_t)b * N_ * K_ + (size_t)n0 * K_;

    f32x4 acc[4][4] = {};

    for (int k0 = 0; k0 < K_; k0 += 32) {
        __syncthreads();
        stage_tile<128>(As, gA + k0, K_);
        stage_tile<128>(Bs, gB + k0, K_);
        __syncthreads();
        s16x8 af[4], bf[4];
        #pragma unroll
        for (int m = 0; m < 4; ++m)
            af[m] = *(const s16x8*)&As[(wm * 64 + m * 16 + l15) * LDA + q * 8];
        #pragma unroll
        for (int n = 0; n < 4; ++n)
            bf[n] = *(const s16x8*)&Bs[(wn * 64 + n * 16 + l15) * LDA + q * 8];
        #pragma unroll
        for (int m = 0; m < 4; ++m)
            #pragma unroll
            for (int n = 0; n < 4; ++n)
                acc[m][n] = __builtin_amdgcn_mfma_f32_16x16x32_bf16(af[m], bf[n], acc[m][n], 0, 0, 0);
    }

    ushort_t* xB = xrt + (size_t)b * N_ * C_;
    #pragma unroll
    for (int m = 0; m < 4; ++m) {
        int cbase = c0 + wm * 64 + m * 16 + 4 * q;
        #pragma unroll
        for (int n = 0; n < 4; ++n) {
            int nn = n0 + wn * 64 + n * 16 + l15;
            s16x4 pk;
            #pragma unroll
            for (int r = 0; r < 4; ++r)
                pk[r] = (short)f2bf(fmaxf(acc[m][n][r], 0.f));
            *(s16x4*)&xB[(size_t)nn * C_ + cbase] = pk;
        }
    }
}

// ============================================================================
// conv2: y[b][o][n] fp32 = sum_c W2[o,c]*xr[c,n]; A=W2b, Bt=xrt. grid (32,4,16)
// ============================================================================
__global__ __launch_bounds__(256)
void conv2_mfma(const ushort_t* __restrict__ W2b, const ushort_t* __restrict__ xrt,
                float* __restrict__ y)
{
    __shared__ ushort_t As[128 * LDA];
    __shared__ ushort_t Bs[128 * LDA];
    const int n0 = blockIdx.x * 128;
    const int o0 = blockIdx.y * 128;
    const int b  = blockIdx.z;
    const int t  = threadIdx.x;
    const int wid = t >> 6, lane = t & 63;
    const int wm = wid >> 1, wn = wid & 1;
    const int l15 = lane & 15, q = lane >> 4;

    const ushort_t* gA = W2b + (size_t)o0 * C_;
    const ushort_t* gB = xrt + (size_t)b * N_ * C_ + (size_t)n0 * C_;

    f32x4 acc[4][4] = {};

    for (int c0 = 0; c0 < C_; c0 += 32) {
        __syncthreads();
        stage_tile<128>(As, gA + c0, C_);
        stage_tile<128>(Bs, gB + c0, C_);
        __syncthreads();
        s16x8 af[4], bf[4];
        #pragma unroll
        for (int m = 0; m < 4; ++m)
            af[m] = *(const s16x8*)&As[(wm * 64 + m * 16 + l15) * LDA + q * 8];
        #pragma unroll
        for (int n = 0; n < 4; ++n)
            bf[n] = *(const s16x8*)&Bs[(wn * 64 + n * 16 + l15) * LDA + q * 8];
        #pragma unroll
        for (int m = 0; m < 4; ++m)
            #pragma unroll
            for (int n = 0; n < 4; ++n)
                acc[m][n] = __builtin_amdgcn_mfma_f32_16x16x32_bf16(af[m], bf[n], acc[m][n], 0, 0, 0);
    }

    float* yB = y + (size_t)b * C_ * N_;
    #pragma unroll
    for (int m = 0; m < 4; ++m) {
        int obase = o0 + wm * 64 + m * 16 + 4 * q;
        #pragma unroll
        for (int n = 0; n < 4; ++n) {
            int nn = n0 + wn * 64 + n * 16 + l15;
            #pragma unroll
            for (int r = 0; r < 4; ++r)
                yB[(size_t)(obase + r) * N_ + nn] = acc[m][n][r];
        }
    }
}

// ============================================================================
// BN stats (per-channel over b,n) -> scale/shift. One block per o.
// ============================================================================
__global__ __launch_bounds__(256)
void bnstats_kernel(const float* __restrict__ y, const float* __restrict__ gamma,
                    const float* __restrict__ beta, float* __restrict__ bnscale,
                    float* __restrict__ bnshift)
{
    int o = blockIdx.x;
    int tid = threadIdx.x;
    float s = 0.f, sq = 0.f;
    for (int b = 0; b < B_; ++b) {
        const float4* p = (const float4*)(y + ((size_t)b * C_ + o) * N_);
        for (int i = tid; i < N_ / 4; i += 256) {
            float4 v = p[i];
            s  += v.x + v.y + v.z + v.w;
            sq += v.x * v.x + v.y * v.y + v.z * v.z + v.w * v.w;
        }
    }
    #pragma unroll
    for (int off = 32; off > 0; off >>= 1) {
        s  += __shfl_xor(s, off);
        sq += __shfl_xor(sq, off);
    }
    __shared__ float rs[4], rq[4];
    int wid = tid >> 6, lane = tid & 63;
    if (lane == 0) { rs[wid] = s; rq[wid] = sq; }
    __syncthreads();
    if (tid == 0) {
        float ts = rs[0] + rs[1] + rs[2] + rs[3];
        float tq = rq[0] + rq[1] + rq[2] + rq[3];
        const float inv_n = 1.f / (float)(B_ * N_);
        float mean = ts * inv_n;
        float var  = tq * inv_n - mean * mean;
        float istd = rsqrtf(var + 1e-5f);
        bnscale[o] = gamma[o] * istd;
        bnshift[o] = beta[o] - gamma[o] * istd * mean;
    }
}

// ============================================================================
// final: out = relu(y*scale + shift + x), in place over y (= d_out)
// ============================================================================
__global__ __launch_bounds__(256)
void bnout_kernel(float* __restrict__ y, const float* __restrict__ x,
                  const float* __restrict__ bnscale, const float* __restrict__ bnshift)
{
    size_t i = (size_t)blockIdx.x * 256 + threadIdx.x;   // float4 index
    float4 vy = ((float4*)y)[i];
    float4 vx = ((const float4*)x)[i];
    int o = (int)((i >> 10) & (C_ - 1));
    float sc = bnscale[o], sh = bnshift[o];
    float4 r;
    r.x = fmaxf(fmaf(vy.x, sc, sh) + vx.x, 0.f);
    r.y = fmaxf(fmaf(vy.y, sc, sh) + vx.y, 0.f);
    r.z = fmaxf(fmaf(vy.z, sc, sh) + vx.z, 0.f);
    r.w = fmaxf(fmaf(vy.w, sc, sh) + vx.w, 0.f);
    ((float4*)y)[i] = r;
}

// ============================================================================
extern "C" void kernel_launch(void* const* d_in, const int* in_sizes, int n_in,
                              void* d_out, int out_size, void* d_ws, size_t ws_size,
                              hipStream_t stream)
{
    const float* x     = (const float*)d_in[0];
    const float* W1    = (const float*)d_in[1];
    const float* b1    = (const float*)d_in[2];
    const float* W2    = (const float*)d_in[3];
    const float* gamma = (const float*)d_in[4];
    const float* beta  = (const float*)d_in[5];
    const float* mu0   = (const float*)d_in[6];

    // workspace layout (~146 MB)
    char* w = (char*)d_ws;
    ushort_t* xf   = (ushort_t*)w;  w += (size_t)B_ * C_ * N_ * 2;   // 67.1 MB (later xrt)
    ushort_t* xft  = (ushort_t*)w;  w += (size_t)B_ * N_ * C_ * 2;   // 67.1 MB
    ushort_t* zs   = (ushort_t*)w;  w += (size_t)B_ * N_ * K_ * 2;   // 8.4 MB
    ushort_t* W1b  = (ushort_t*)w;  w += (size_t)C_ * C_ * 2;
    ushort_t* W2b  = (ushort_t*)w;  w += (size_t)C_ * C_ * 2;
    ushort_t* mu_t = (ushort_t*)w;  w += (size_t)B_ * K_ * C_ * 2;
    ushort_t* mu_b = (ushort_t*)w;  w += (size_t)B_ * C_ * K_ * 2;
    float* invcs   = (float*)w;     w += (size_t)B_ * K_ * 4;
    float* bnscale = (float*)w;     w += C_ * 4;
    float* bnshift = (float*)w;     w += C_ * 4;

    ushort_t* xrt = xf;   // alias: xf dead after EM loop

    float* y         = (float*)d_out;                    // conv2 out / final out
    float* mu_out    = (float*)d_out + (size_t)B_ * C_ * N_;
    float* theta_out = mu_out + (size_t)B_ * C_ * K_;
    float* macc      = y;                                // first 2 MB of y region (EM only)
    float* zst       = y + (size_t)8 * 1024 * 1024;      // fp32 z [b][k][n], 16.8 MB @ +32MB

    cvtW_kernel<<<256, 256, 0, stream>>>(W1, W2, W1b, W2b);
    initmu_kernel<<<128, 256, 0, stream>>>(mu0, mu_t);

    conv1_mfma<<<dim3(32, 4, 16), 256, 0, stream>>>(W1b, x, b1, xf, xft);

    for (int s = 0; s < 2; ++s) {
        zgemm_mfma<<<dim3(32, 1, 16), 256, 0, stream>>>(mu_t, xft, zst, s == 0 ? 0 : K_ * C_);
        softmax_col<<<dim3(16, 16), 256, 0, stream>>>(zst);
        colsum_t<<<256, 256, 0, stream>>>(zst, invcs);
        hipMemsetAsync(macc, 0, (size_t)B_ * K_ * C_ * 4, stream);
        mugemm_mfma<<<dim3(8, 4, 16), 256, 0, stream>>>(zst, xf, invcs, macc);
        l2norm_t<<<256, 256, 0, stream>>>(macc, mu_t, mu_b, mu_out, theta_out);
    }

    ztr_kernel<<<dim3(64, 16), 256, 0, stream>>>(zst, zs);
    recon_mfma<<<dim3(32, 4, 16), 256, 0, stream>>>(mu_b, zs, xrt);
    conv2_mfma<<<dim3(32, 4, 16), 256, 0, stream>>>(W2b, xrt, y);
    bnstats_kernel<<<C_, 256, 0, stream>>>(y, gamma, beta, bnscale, bnshift);
    bnout_kernel<<<dim3(B_ * C_ * N_ / 4 / 256), 256, 0, stream>>>(y, x, bnscale, bnshift);
}

// Round 4
// 573.384 us; speedup vs baseline: 3.3360x; 1.0672x over previous
//
#include <hip/hip_runtime.h>
#include <hip/hip_bf16.h>

#define B_ 16
#define C_ 512
#define K_ 64
#define N_ 4096   // H*W
#define LDA 40    // 32 shorts + 8 pad: row stride 80B -> <=2-way bank aliasing (free)

typedef unsigned short ushort_t;
typedef __attribute__((ext_vector_type(8))) short s16x8;
typedef __attribute__((ext_vector_type(4))) short s16x4;
typedef __attribute__((ext_vector_type(4))) float f32x4;

__device__ inline ushort_t f2bf(float f) {            // RNE
    unsigned int u = __builtin_bit_cast(unsigned int, f);
    u = (u + 0x7FFFu + ((u >> 16) & 1u)) >> 16;
    return (ushort_t)u;
}
__device__ inline ushort_t f2bf_fast(float f) {       // round-half-up (bulk staging)
    unsigned int u = __builtin_bit_cast(unsigned int, f);
    return (ushort_t)((u + 0x8000u) >> 16);
}
__device__ inline float bf2f(ushort_t h) {
    unsigned int u = ((unsigned int)h) << 16;
    return __builtin_bit_cast(float, u);
}

// Stage R x 32 bf16 tile (row-major, contraction contiguous) into padded LDS.
template<int R>
__device__ inline void stage_tile(ushort_t* lds, const ushort_t* g, int gstride) {
    const int t = threadIdx.x;
    #pragma unroll
    for (int l = 0; l < R / 64; ++l) {
        int ch = t + l * 256;
        int row = ch >> 2, seg = ch & 3;
        s16x8 v = *(const s16x8*)(g + (size_t)row * gstride + seg * 8);
        *(s16x8*)(lds + row * LDA + seg * 8) = v;
    }
}

// ============================================================================
// cvt W1,W2 -> bf16
// ============================================================================
__global__ __launch_bounds__(256)
void cvtW_kernel(const float* __restrict__ W1, const float* __restrict__ W2,
                 ushort_t* __restrict__ W1b, ushort_t* __restrict__ W2b)
{
    int idx = blockIdx.x * 256 + threadIdx.x;   // 0..65535, 8 floats each
    const float* s; ushort_t* d; int off;
    if (idx < 32768) { s = W1; d = W1b; off = idx * 8; }
    else             { s = W2; d = W2b; off = (idx - 32768) * 8; }
    float4 a = *(const float4*)(s + off);
    float4 b = *(const float4*)(s + off + 4);
    s16x8 v;
    v[0] = (short)f2bf(a.x); v[1] = (short)f2bf(a.y);
    v[2] = (short)f2bf(a.z); v[3] = (short)f2bf(a.w);
    v[4] = (short)f2bf(b.x); v[5] = (short)f2bf(b.y);
    v[6] = (short)f2bf(b.z); v[7] = (short)f2bf(b.w);
    *(s16x8*)(d + off) = v;
}

// ============================================================================
// initmu: mu0 fp32 [c][k] -> mu_t bf16 [k][c]
// ============================================================================
__global__ __launch_bounds__(256)
void initmu_kernel(const float* __restrict__ mu0, ushort_t* __restrict__ mu_t)
{
    int idx = blockIdx.x * 256 + threadIdx.x;   // c = idx>>6, k = idx&63
    float v = mu0[idx];
    mu_t[(idx & 63) * C_ + (idx >> 6)] = f2bf(v);
}

// ============================================================================
// conv1: xf[b][o][n] bf16 = sum_c W1[o,c]*x[b,c,n] + b1[o]; also xft [n][o].
// A = W1b[o][c] bf16; B staged by in-kernel transpose of fp32 x (4x4 reg blocks)
// grid (32, 4, 16), 256 thr, 4 waves (2x2), wave 64x64  [unchanged from r3]
// ============================================================================
__global__ __launch_bounds__(256)
void conv1_mfma(const ushort_t* __restrict__ W1b, const float* __restrict__ x,
                const float* __restrict__ b1, ushort_t* __restrict__ xf,
                ushort_t* __restrict__ xft)
{
    __shared__ ushort_t As[128 * LDA];
    __shared__ ushort_t Bs[128 * LDA];
    const int n0 = blockIdx.x * 128;
    const int o0 = blockIdx.y * 128;
    const int b  = blockIdx.z;
    const int t  = threadIdx.x;
    const int wid = t >> 6, lane = t & 63;
    const int wm = wid >> 1, wn = wid & 1;
    const int l15 = lane & 15, q = lane >> 4;

    const ushort_t* gA = W1b + (size_t)o0 * C_;
    const float*    xB = x + (size_t)b * C_ * N_ + n0;
    const int cg = t >> 5, ng = t & 31;   // transpose-stage coords

    f32x4 acc[4][4] = {};

    for (int c0 = 0; c0 < C_; c0 += 32) {
        __syncthreads();
        stage_tile<128>(As, gA + c0, C_);
        {   // B: transpose-stage x[c0+cg*4 .. +4)[n0+ng*4 .. +4) -> Bs[n][c]
            const float* src = xB + (size_t)(c0 + cg * 4) * N_ + ng * 4;
            float4 f0 = *(const float4*)(src);
            float4 f1 = *(const float4*)(src + N_);
            float4 f2 = *(const float4*)(src + 2 * N_);
            float4 f3 = *(const float4*)(src + 3 * N_);
            ushort_t* dst = Bs + (ng * 4) * LDA + cg * 4;
            s16x4 v;
            v[0] = (short)f2bf_fast(f0.x); v[1] = (short)f2bf_fast(f1.x);
            v[2] = (short)f2bf_fast(f2.x); v[3] = (short)f2bf_fast(f3.x);
            *(s16x4*)(dst) = v;
            v[0] = (short)f2bf_fast(f0.y); v[1] = (short)f2bf_fast(f1.y);
            v[2] = (short)f2bf_fast(f2.y); v[3] = (short)f2bf_fast(f3.y);
            *(s16x4*)(dst + LDA) = v;
            v[0] = (short)f2bf_fast(f0.z); v[1] = (short)f2bf_fast(f1.z);
            v[2] = (short)f2bf_fast(f2.z); v[3] = (short)f2bf_fast(f3.z);
            *(s16x4*)(dst + 2 * LDA) = v;
            v[0] = (short)f2bf_fast(f0.w); v[1] = (short)f2bf_fast(f1.w);
            v[2] = (short)f2bf_fast(f2.w); v[3] = (short)f2bf_fast(f3.w);
            *(s16x4*)(dst + 3 * LDA) = v;
        }
        __syncthreads();
        s16x8 af[4], bf[4];
        #pragma unroll
        for (int m = 0; m < 4; ++m)
            af[m] = *(const s16x8*)&As[(wm * 64 + m * 16 + l15) * LDA + q * 8];
        #pragma unroll
        for (int n = 0; n < 4; ++n)
            bf[n] = *(const s16x8*)&Bs[(wn * 64 + n * 16 + l15) * LDA + q * 8];
        #pragma unroll
        for (int m = 0; m < 4; ++m)
            #pragma unroll
            for (int n = 0; n < 4; ++n)
                acc[m][n] = __builtin_amdgcn_mfma_f32_16x16x32_bf16(af[m], bf[n], acc[m][n], 0, 0, 0);
    }

    ushort_t* xfB  = xf  + (size_t)b * C_ * N_;
    ushort_t* xftB = xft + (size_t)b * N_ * C_;
    #pragma unroll
    for (int m = 0; m < 4; ++m) {
        int obase = o0 + wm * 64 + m * 16 + 4 * q;
        float bv[4];
        #pragma unroll
        for (int r = 0; r < 4; ++r) bv[r] = b1[obase + r];
        #pragma unroll
        for (int n = 0; n < 4; ++n) {
            int nn = n0 + wn * 64 + n * 16 + l15;
            s16x4 pk;
            #pragma unroll
            for (int r = 0; r < 4; ++r) {
                ushort_t h = f2bf(acc[m][n][r] + bv[r]);
                pk[r] = (short)h;
                xfB[(size_t)(obase + r) * N_ + nn] = h;
            }
            *(s16x4*)&xftB[(size_t)nn * C_ + obase] = pk;
        }
    }
}

// ============================================================================
// zfused: z[b,n,k] GEMM + column softmax/blend + colsum + dual-layout write.
// A = mu_t[k][c] bf16 (batch stride), Bt = xft[n][c] bf16.
// grid (32, 16): block = 128 n x full K=64.
// Epilogue: acc -> LDS fp32 -> per-column (max, sum e, ||z||) -> writes
//   zst bf16 [k][n] (for mugemm), zs bf16 [n][k] (for recon), cs[b][k] atomics.
// ============================================================================
__global__ __launch_bounds__(256)
void zfused_mfma(const ushort_t* __restrict__ mu_t, const ushort_t* __restrict__ xft,
                 ushort_t* __restrict__ zst, ushort_t* __restrict__ zs,
                 float* __restrict__ cs, int mustride)
{
    __shared__ char pool[64 * 133 * 4 + 64 * 132 * 2 + 128 * 2 * 4];
    float*    zt  = (float*)pool;                              // [64][133] fp32 z
    ushort_t* zb  = (ushort_t*)(pool + 64 * 133 * 4);          // [64][132] bf16 e
    float*    csb = (float*)(pool + 64 * 133 * 4 + 64 * 132 * 2); // [128][2] scale,bias
    ushort_t* As  = (ushort_t*)pool;                           // loop-time alias
    ushort_t* Bs  = (ushort_t*)(pool + 64 * LDA * 2);

    const int n0 = blockIdx.x * 128;
    const int b  = blockIdx.y;
    const int t  = threadIdx.x;
    const int wid = t >> 6, lane = t & 63;
    const int wm = wid >> 1, wn = wid & 1;
    const int l15 = lane & 15, q = lane >> 4;

    const ushort_t* gA = mu_t + (size_t)b * mustride;
    const ushort_t* gB = xft + (size_t)b * N_ * C_ + (size_t)n0 * C_;

    f32x4 acc[2][4] = {};

    for (int c0 = 0; c0 < C_; c0 += 32) {
        __syncthreads();
        stage_tile<64>(As, gA + c0, C_);
        stage_tile<128>(Bs, gB + c0, C_);
        __syncthreads();
        s16x8 af[2], bf[4];
        #pragma unroll
        for (int m = 0; m < 2; ++m)
            af[m] = *(const s16x8*)&As[(wm * 32 + m * 16 + l15) * LDA + q * 8];
        #pragma unroll
        for (int n = 0; n < 4; ++n)
            bf[n] = *(const s16x8*)&Bs[(wn * 64 + n * 16 + l15) * LDA + q * 8];
        #pragma unroll
        for (int m = 0; m < 2; ++m)
            #pragma unroll
            for (int n = 0; n < 4; ++n)
                acc[m][n] = __builtin_amdgcn_mfma_f32_16x16x32_bf16(af[m], bf[n], acc[m][n], 0, 0, 0);
    }

    __syncthreads();   // As/Bs dead; pool becomes zt/zb/csb
    // phase B: acc -> zt[k][n-local]
    #pragma unroll
    for (int m = 0; m < 2; ++m) {
        int kbase = wm * 32 + m * 16 + 4 * q;
        #pragma unroll
        for (int n = 0; n < 4; ++n) {
            int nl = wn * 64 + n * 16 + l15;
            #pragma unroll
            for (int r = 0; r < 4; ++r)
                zt[(kbase + r) * 133 + nl] = acc[m][n][r];
        }
    }
    __syncthreads();
    // phase C: per-column softmax prep (threads 0..127 each own column n-local=t)
    if (t < 128) {
        const float* col = zt + t;
        float mx = -1e30f, sq = 0.f;
        #pragma unroll
        for (int k = 0; k < K_; ++k) {
            float v = col[k * 133];
            mx = fmaxf(mx, v);
            sq += v * v;
        }
        float se = 0.f;
        #pragma unroll
        for (int k = 0; k < K_; ++k) {
            float e = __expf(col[k * 133] - mx);
            se += e;
            zb[k * 132 + t] = f2bf(e);
        }
        csb[t * 2]     = 0.5f / se;                                  // scale
        csb[t * 2 + 1] = 0.5f * 64.f / (63.f + 2.f * sqrtf(sq));     // blend bias
    }
    __syncthreads();
    // phase D job1: zst[k][n] rows (coalesced) + per-k colsum atomics
    ushort_t* zstB = zst + (size_t)b * K_ * N_;
    #pragma unroll
    for (int i = 0; i < 4; ++i) {
        int ch = t + 256 * i;          // 1024 chunks: k = ch>>4, seg = ch&15
        int k = ch >> 4, seg = ch & 15;
        s16x8 e8 = *(const s16x8*)&zb[k * 132 + seg * 8];
        s16x8 o8;
        float sum = 0.f;
        #pragma unroll
        for (int j = 0; j < 8; ++j) {
            int nl = seg * 8 + j;
            float v = fmaf(bf2f((ushort_t)e8[j]), csb[nl * 2], csb[nl * 2 + 1]);
            sum += v;
            o8[j] = (short)f2bf(v);
        }
        *(s16x8*)&zstB[(size_t)k * N_ + n0 + seg * 8] = o8;
        #pragma unroll
        for (int off = 1; off < 16; off <<= 1) sum += __shfl_xor(sum, off);
        if ((t & 15) == 0) atomicAdd(&cs[b * K_ + k], sum);
    }
    // phase D job2: zs[n][k] rows (coalesced)
    ushort_t* zsB = zs + (size_t)b * N_ * K_;
    #pragma unroll
    for (int i = 0; i < 4; ++i) {
        int ch = t + 256 * i;          // 1024 chunks: n = ch>>3, kseg = ch&7
        int nl = ch >> 3, kseg = ch & 7;
        float sc = csb[nl * 2], bl = csb[nl * 2 + 1];
        s16x8 o8;
        #pragma unroll
        for (int j = 0; j < 8; ++j) {
            int j2 = (j + nl) & 7;     // stagger scalar LDS reads
            float v = fmaf(bf2f(zb[(kseg * 8 + j2) * 132 + nl]), sc, bl);
            o8[j2] = (short)f2bf(v);
        }
        *(s16x8*)&zsB[(size_t)(n0 + nl) * K_ + kseg * 8] = o8;
    }
}

// ============================================================================
// mugemm: macc[b][k][c] fp32 (atomic) += (1/(1e-6+cs[k]))*sum_n z[k,n]*xf[c,n]
// A = zst[k][n] bf16, Bt = xf[c][n] bf16; split over n: grid (8, 4, 16)
// ============================================================================
__global__ __launch_bounds__(256)
void mugemm_mfma(const ushort_t* __restrict__ zst, const ushort_t* __restrict__ xf,
                 const float* __restrict__ cs, float* __restrict__ macc)
{
    __shared__ ushort_t As[64 * LDA];
    __shared__ ushort_t Bs[128 * LDA];
    const int ns = blockIdx.x * 512;
    const int c0 = blockIdx.y * 128;
    const int b  = blockIdx.z;
    const int t  = threadIdx.x;
    const int wid = t >> 6, lane = t & 63;
    const int wm = wid >> 1, wn = wid & 1;
    const int l15 = lane & 15, q = lane >> 4;

    const ushort_t* gA = zst + (size_t)b * K_ * N_ + ns;
    const ushort_t* gB = xf + (size_t)b * C_ * N_ + (size_t)c0 * N_ + ns;

    f32x4 acc[2][4] = {};

    for (int nn0 = 0; nn0 < 512; nn0 += 32) {
        __syncthreads();
        stage_tile<64>(As, gA + nn0, N_);
        stage_tile<128>(Bs, gB + nn0, N_);
        __syncthreads();
        s16x8 af[2], bf[4];
        #pragma unroll
        for (int m = 0; m < 2; ++m)
            af[m] = *(const s16x8*)&As[(wm * 32 + m * 16 + l15) * LDA + q * 8];
        #pragma unroll
        for (int n = 0; n < 4; ++n)
            bf[n] = *(const s16x8*)&Bs[(wn * 64 + n * 16 + l15) * LDA + q * 8];
        #pragma unroll
        for (int m = 0; m < 2; ++m)
            #pragma unroll
            for (int n = 0; n < 4; ++n)
                acc[m][n] = __builtin_amdgcn_mfma_f32_16x16x32_bf16(af[m], bf[n], acc[m][n], 0, 0, 0);
    }

    float* mB = macc + (size_t)b * K_ * C_;
    #pragma unroll
    for (int m = 0; m < 2; ++m) {
        int kbase = wm * 32 + m * 16 + 4 * q;
        float ic[4];
        #pragma unroll
        for (int r = 0; r < 4; ++r) ic[r] = 1.f / (1e-6f + cs[b * K_ + kbase + r]);
        #pragma unroll
        for (int n = 0; n < 4; ++n) {
            int cc = c0 + wn * 64 + n * 16 + l15;
            #pragma unroll
            for (int r = 0; r < 4; ++r)
                atomicAdd(&mB[(size_t)(kbase + r) * C_ + cc], acc[m][n][r] * ic[r]);
        }
    }
}

// ============================================================================
// l2norm over c: mu_t bf16 [k][c], mu_b bf16 [c][k], mu_out fp32 [c][k], theta
// wave per (b,k)
// ============================================================================
__global__ __launch_bounds__(256)
void l2norm_t(const float* __restrict__ macc, ushort_t* __restrict__ mu_t,
              ushort_t* __restrict__ mu_b, float* __restrict__ mu_out,
              float* __restrict__ theta_out)
{
    int wid  = blockIdx.x * 4 + (threadIdx.x >> 6);
    int lane = threadIdx.x & 63;
    int b = wid >> 6, k = wid & 63;
    const float* src = macc + (size_t)b * K_ * C_ + (size_t)k * C_;
    float v[8], s = 0.f;
    #pragma unroll
    for (int i = 0; i < 8; ++i) { v[i] = src[lane + i * 64]; s += v[i] * v[i]; }
    #pragma unroll
    for (int off = 32; off > 0; off >>= 1) s += __shfl_xor(s, off);
    float inv = 1.f / (1e-6f + sqrtf(s));
    ushort_t* mt = mu_t + (size_t)b * K_ * C_ + (size_t)k * C_;
    ushort_t* mb = mu_b + (size_t)b * C_ * K_ + k;
    float*    mo = mu_out + (size_t)b * C_ * K_ + k;
    #pragma unroll
    for (int i = 0; i < 8; ++i) {
        int c = lane + i * 64;
        float val = v[i] * inv;
        mt[c] = f2bf(val);
        mb[(size_t)c * K_] = f2bf(val);
        mo[(size_t)c * K_] = val;
    }
    if (wid == 0 && lane == 0) *theta_out = 45.0f;
}

// ============================================================================
// recon: xrt[n][c] bf16 = relu(sum_k mu[c,k]*z[n,k])
// A = mu_b[c][k], Bt = zs[n][k]; grid (32, 4, 16)
// ============================================================================
__global__ __launch_bounds__(256)
void recon_mfma(const ushort_t* __restrict__ mu_b, const ushort_t* __restrict__ zs,
                ushort_t* __restrict__ xrt)
{
    __shared__ ushort_t As[128 * LDA];
    __shared__ ushort_t Bs[128 * LDA];
    const int n0 = blockIdx.x * 128;
    const int c0 = blockIdx.y * 128;
    const int b  = blockIdx.z;
    const int t  = threadIdx.x;
    const int wid = t >> 6, lane = t & 63;
    const int wm = wid >> 1, wn = wid & 1;
    const int l15 = lane & 15, q = lane >> 4;

    const ushort_t* gA = mu_b + (size_t)b * C_ * K_ + (size_t)c0 * K_;
    const ushort_t* gB = zs + (size_t)b * N_ * K_ + (size_t)n0 * K_;

    f32x4 acc[4][4] = {};

    for (int k0 = 0; k0 < K_; k0 += 32) {
        __syncthreads();
        stage_tile<128>(As, gA + k0, K_);
        stage_tile<128>(Bs, gB + k0, K_);
        __syncthreads();
        s16x8 af[4], bf[4];
        #pragma unroll
        for (int m = 0; m < 4; ++m)
            af[m] = *(const s16x8*)&As[(wm * 64 + m * 16 + l15) * LDA + q * 8];
        #pragma unroll
        for (int n = 0; n < 4; ++n)
            bf[n] = *(const s16x8*)&Bs[(wn * 64 + n * 16 + l15) * LDA + q * 8];
        #pragma unroll
        for (int m = 0; m < 4; ++m)
            #pragma unroll
            for (int n = 0; n < 4; ++n)
                acc[m][n] = __builtin_amdgcn_mfma_f32_16x16x32_bf16(af[m], bf[n], acc[m][n], 0, 0, 0);
    }

    ushort_t* xB = xrt + (size_t)b * N_ * C_;
    #pragma unroll
    for (int m = 0; m < 4; ++m) {
        int cbase = c0 + wm * 64 + m * 16 + 4 * q;
        #pragma unroll
        for (int n = 0; n < 4; ++n) {
            int nn = n0 + wn * 64 + n * 16 + l15;
            s16x4 pk;
            #pragma unroll
            for (int r = 0; r < 4; ++r)
                pk[r] = (short)f2bf(fmaxf(acc[m][n][r], 0.f));
            *(s16x4*)&xB[(size_t)nn * C_ + cbase] = pk;
        }
    }
}

// ============================================================================
// conv2: y[b][o][n] fp32 = sum_c W2[o,c]*xr[c,n]; A=W2b, Bt=xrt. grid (32,4,16)
// Fused BN partial stats: atomics into ysum[o], ysq[o].
// ============================================================================
__global__ __launch_bounds__(256)
void conv2_mfma(const ushort_t* __restrict__ W2b, const ushort_t* __restrict__ xrt,
                float* __restrict__ y, float* __restrict__ ysum, float* __restrict__ ysq)
{
    __shared__ ushort_t As[128 * LDA];
    __shared__ ushort_t Bs[128 * LDA];
    __shared__ float sums[128][2];
    const int n0 = blockIdx.x * 128;
    const int o0 = blockIdx.y * 128;
    const int b  = blockIdx.z;
    const int t  = threadIdx.x;
    const int wid = t >> 6, lane = t & 63;
    const int wm = wid >> 1, wn = wid & 1;
    const int l15 = lane & 15, q = lane >> 4;

    const ushort_t* gA = W2b + (size_t)o0 * C_;
    const ushort_t* gB = xrt + (size_t)b * N_ * C_ + (size_t)n0 * C_;

    f32x4 acc[4][4] = {};

    for (int c0 = 0; c0 < C_; c0 += 32) {
        __syncthreads();
        stage_tile<128>(As, gA + c0, C_);
        stage_tile<128>(Bs, gB + c0, C_);
        __syncthreads();
        s16x8 af[4], bf[4];
        #pragma unroll
        for (int m = 0; m < 4; ++m)
            af[m] = *(const s16x8*)&As[(wm * 64 + m * 16 + l15) * LDA + q * 8];
        #pragma unroll
        for (int n = 0; n < 4; ++n)
            bf[n] = *(const s16x8*)&Bs[(wn * 64 + n * 16 + l15) * LDA + q * 8];
        #pragma unroll
        for (int m = 0; m < 4; ++m)
            #pragma unroll
            for (int n = 0; n < 4; ++n)
                acc[m][n] = __builtin_amdgcn_mfma_f32_16x16x32_bf16(af[m], bf[n], acc[m][n], 0, 0, 0);
    }

    float* yB = y + (size_t)b * C_ * N_;
    float ps[4][4], pq[4][4];
    #pragma unroll
    for (int m = 0; m < 4; ++m) {
        int obase = o0 + wm * 64 + m * 16 + 4 * q;
        #pragma unroll
        for (int r = 0; r < 4; ++r) { ps[m][r] = 0.f; pq[m][r] = 0.f; }
        #pragma unroll
        for (int n = 0; n < 4; ++n) {
            int nn = n0 + wn * 64 + n * 16 + l15;
            #pragma unroll
            for (int r = 0; r < 4; ++r) {
                float v = acc[m][n][r];
                yB[(size_t)(obase + r) * N_ + nn] = v;
                ps[m][r] += v;
                pq[m][r] = fmaf(v, v, pq[m][r]);
            }
        }
    }
    // reduce over l15 (n within wave)
    #pragma unroll
    for (int m = 0; m < 4; ++m)
        #pragma unroll
        for (int r = 0; r < 4; ++r)
            #pragma unroll
            for (int off = 1; off < 16; off <<= 1) {
                ps[m][r] += __shfl_xor(ps[m][r], off);
                pq[m][r] += __shfl_xor(pq[m][r], off);
            }
    __syncthreads();
    if (l15 == 0 && wn == 0) {
        #pragma unroll
        for (int m = 0; m < 4; ++m)
            #pragma unroll
            for (int r = 0; r < 4; ++r) {
                int ol = wm * 64 + m * 16 + 4 * q + r;
                sums[ol][0] = ps[m][r];
                sums[ol][1] = pq[m][r];
            }
    }
    __syncthreads();
    if (l15 == 0 && wn == 1) {
        #pragma unroll
        for (int m = 0; m < 4; ++m)
            #pragma unroll
            for (int r = 0; r < 4; ++r) {
                int ol = wm * 64 + m * 16 + 4 * q + r;
                sums[ol][0] += ps[m][r];
                sums[ol][1] += pq[m][r];
            }
    }
    __syncthreads();
    if (t < 128) {
        atomicAdd(&ysum[o0 + t], sums[t][0]);
        atomicAdd(&ysq[o0 + t],  sums[t][1]);
    }
}

// ============================================================================
// final: out = relu(y*scale + shift + x), in place; scale/shift from ysum/ysq
// ============================================================================
__global__ __launch_bounds__(256)
void bnout_kernel(float* __restrict__ y, const float* __restrict__ x,
                  const float* __restrict__ gamma, const float* __restrict__ beta,
                  const float* __restrict__ ysum, const float* __restrict__ ysq)
{
    size_t i = (size_t)blockIdx.x * 256 + threadIdx.x;   // float4 index
    float4 vy = ((float4*)y)[i];
    float4 vx = ((const float4*)x)[i];
    int o = (int)((i >> 10) & (C_ - 1));
    const float inv_n = 1.f / (float)(B_ * N_);
    float mean = ysum[o] * inv_n;
    float var  = ysq[o] * inv_n - mean * mean;
    float istd = rsqrtf(var + 1e-5f);
    float sc = gamma[o] * istd;
    float sh = beta[o] - sc * mean;
    float4 r;
    r.x = fmaxf(fmaf(vy.x, sc, sh) + vx.x, 0.f);
    r.y = fmaxf(fmaf(vy.y, sc, sh) + vx.y, 0.f);
    r.z = fmaxf(fmaf(vy.z, sc, sh) + vx.z, 0.f);
    r.w = fmaxf(fmaf(vy.w, sc, sh) + vx.w, 0.f);
    ((float4*)y)[i] = r;
}

// ============================================================================
extern "C" void kernel_launch(void* const* d_in, const int* in_sizes, int n_in,
                              void* d_out, int out_size, void* d_ws, size_t ws_size,
                              hipStream_t stream)
{
    const float* x     = (const float*)d_in[0];
    const float* W1    = (const float*)d_in[1];
    const float* b1    = (const float*)d_in[2];
    const float* W2    = (const float*)d_in[3];
    const float* gamma = (const float*)d_in[4];
    const float* beta  = (const float*)d_in[5];
    const float* mu0   = (const float*)d_in[6];

    // workspace layout (~139.5 MB)
    char* w = (char*)d_ws;
    ushort_t* xf   = (ushort_t*)w;  w += (size_t)B_ * C_ * N_ * 2;   // 67.1 MB (later xrt)
    ushort_t* xft  = (ushort_t*)w;  w += (size_t)B_ * N_ * C_ * 2;   // 67.1 MB
    ushort_t* W1b  = (ushort_t*)w;  w += (size_t)C_ * C_ * 2;
    ushort_t* W2b  = (ushort_t*)w;  w += (size_t)C_ * C_ * 2;
    ushort_t* mu_t = (ushort_t*)w;  w += (size_t)B_ * K_ * C_ * 2;
    ushort_t* mu_b = (ushort_t*)w;  w += (size_t)B_ * C_ * K_ * 2;
    float* cs      = (float*)w;     w += (size_t)B_ * K_ * 4;        // colsum accum
    float* macc    = (float*)w;     w += (size_t)B_ * K_ * C_ * 4;   // 2 MB (contig w/ cs)
    float* ysum    = (float*)w;     w += C_ * 4;
    float* ysq     = (float*)w;     w += C_ * 4;

    ushort_t* xrt = xf;   // alias: xf dead after stage-2 mugemm

    float* y         = (float*)d_out;                    // conv2 out / final out
    float* mu_out    = (float*)d_out + (size_t)B_ * C_ * N_;
    float* theta_out = mu_out + (size_t)B_ * C_ * K_;
    // z buffers live inside the (dead-during-EM) y region of d_out
    ushort_t* zst = (ushort_t*)(y + (size_t)8  * 1024 * 1024);  // bf16 [b][k][n], 8.4 MB
    ushort_t* zs  = (ushort_t*)(y + (size_t)16 * 1024 * 1024);  // bf16 [b][n][k], 8.4 MB

    cvtW_kernel<<<256, 256, 0, stream>>>(W1, W2, W1b, W2b);
    initmu_kernel<<<128, 256, 0, stream>>>(mu0, mu_t);
    hipMemsetAsync(ysum, 0, 2 * C_ * 4, stream);

    conv1_mfma<<<dim3(32, 4, 16), 256, 0, stream>>>(W1b, x, b1, xf, xft);

    for (int s = 0; s < 2; ++s) {
        // zero cs + macc (contiguous)
        hipMemsetAsync(cs, 0, (size_t)B_ * K_ * 4 + (size_t)B_ * K_ * C_ * 4, stream);
        zfused_mfma<<<dim3(32, 16), 256, 0, stream>>>(mu_t, xft, zst, zs, cs,
                                                      s == 0 ? 0 : K_ * C_);
        mugemm_mfma<<<dim3(8, 4, 16), 256, 0, stream>>>(zst, xf, cs, macc);
        l2norm_t<<<256, 256, 0, stream>>>(macc, mu_t, mu_b, mu_out, theta_out);
    }

    recon_mfma<<<dim3(32, 4, 16), 256, 0, stream>>>(mu_b, zs, xrt);
    conv2_mfma<<<dim3(32, 4, 16), 256, 0, stream>>>(W2b, xrt, y, ysum, ysq);
    bnout_kernel<<<dim3(B_ * C_ * N_ / 4 / 256), 256, 0, stream>>>(y, x, gamma, beta, ysum, ysq);
}